// Round 4
// baseline (411.513 us; speedup 1.0000x reference)
//
#include <hip/hip_runtime.h>

// Deformable conv fusion v4: split-N, barrier-free, all-MFMA.
// - 4096 independent waves (2048 blocks x 2 waves), each owning a
//   16px x 128oc output tile (nh = N-half). No barriers, no reduction.
// - Phase A (offset 1x1 conv) as 8x5 MFMA with bias-initialized acc,
//   w_off pre-packed to B-frag layout in d_ws.
// - Main loop: 72 chunks, register-direct bilinear A-frag gather
//   (2 passes of 4 named float4 corner regs - no spillable arrays),
//   B-frags direct from packed w2 (L2-resident), 8 MFMA/chunk.

constexpr int H_ = 64, W_ = 256;
constexpr int HWsz = H_ * W_;
constexpr int OC_ = 256;
constexpr int WMAIN_ELEMS = 72 * 16 * 64 * 8;   // 589824 main-conv B frags
constexpr int WOFFB_ELEMS = 8 * 5 * 64 * 8;     // 20480 phase-A B frags

using f32x4 = __attribute__((ext_vector_type(4))) float;
using s16x8 = __attribute__((ext_vector_type(8))) short;

__device__ __forceinline__ unsigned short f2bf(float f) {
    unsigned u = __float_as_uint(f);
    return (unsigned short)((u + 0x7fffu + ((u >> 16) & 1u)) >> 16);
}

// w2 layout: [0, WMAIN): main frags [gkh 72][t 16][lane 64][j 8]
//   value = w_def[oc = t*16+(lane&15)][cin = g*64+half*32+(lane>>4)*8+j][k]
// [WMAIN, +WOFFB): phase-A frags [c8 8][t 5][lane 64][j 8]
//   value = w_off[o = t*16+(lane&15)][ch = c8*32+(lane>>4)*8+j]  (0 if o>=72)
__global__ __launch_bounds__(256) void wprep_kernel(const float* __restrict__ w_def,
                                                    const float* __restrict__ w_off,
                                                    unsigned short* __restrict__ w2) {
    int i = blockIdx.x * 256 + threadIdx.x;
    if (i < WMAIN_ELEMS) {
        int j = i & 7, lane = (i >> 3) & 63, t = (i >> 9) & 15, gkh = i >> 13;
        int half = gkh & 1, gk = gkh >> 1;
        int k = gk % 9, g = gk / 9;
        int oc = t * 16 + (lane & 15);
        int cin = g * 64 + half * 32 + (lane >> 4) * 8 + j;
        w2[i] = f2bf(w_def[(size_t)oc * 2304 + (size_t)cin * 9 + k]);
    } else if (i < WMAIN_ELEMS + WOFFB_ELEMS) {
        int i2 = i - WMAIN_ELEMS;
        int j = i2 & 7, lane = (i2 >> 3) & 63, idx = i2 >> 9;   // idx = c8*5 + t
        int t = idx % 5, c8 = idx / 5;
        int o = t * 16 + (lane & 15);
        int ch = c8 * 32 + (lane >> 4) * 8 + j;
        float v = (o < 72) ? w_off[o * 256 + ch] : 0.f;
        w2[i] = f2bf(v);
    }
}

template<bool USE_WS>
__global__ __launch_bounds__(128, 4) void deform_kernel(
    const float* __restrict__ x0, const float* __restrict__ x1,
    const float* __restrict__ x2,
    const float* __restrict__ w_off, const float* __restrict__ b_off,
    const float* __restrict__ w_def, const unsigned short* __restrict__ w2,
    float* __restrict__ out)
{
    __shared__ float off_lds[2][72 * 16];   // per-wave offset tiles (9.2 KB)

    const int tid  = threadIdx.x;
    const int lane = tid & 63;
    const int wv   = tid >> 6;
    const int wtile = blockIdx.x * 2 + wv;   // 0..4095
    const int nh = wtile & 1;                // N-half: oc base = nh*128
    const int pt = wtile >> 1;               // pixel tile 0..2047
    const int ws_ = pt & 15;
    const int h   = (pt >> 4) & 63;
    const int b   = pt >> 10;
    const int p   = lane & 15;               // this lane's pixel (A row)
    const int cq  = lane >> 4;               // channel quad
    const int pix = h * W_ + ws_ * 16;

    const float* xA = x0 + (size_t)b * 64  * HWsz;
    const float* xB = x1 + (size_t)b * 64  * HWsz;
    const float* xC = x2 + (size_t)b * 128 * HWsz;

    // ---- Phase A: offsets via MFMA (16px x 256ch) @ (256ch x 80off) ----
    f32x4 oa[5];
    #pragma unroll
    for (int t = 0; t < 5; ++t) {
        int o = t * 16 + p;                  // D col = lane&15
        float bv = (o < 72) ? b_off[o] : 0.f;
        oa[t][0] = bv; oa[t][1] = bv; oa[t][2] = bv; oa[t][3] = bv;
    }
    #pragma unroll
    for (int c8 = 0; c8 < 8; ++c8) {
        const float* src = (c8 < 2) ? xA + (size_t)c8 * 32 * HWsz
                         : (c8 < 4) ? xB + (size_t)(c8 - 2) * 32 * HWsz
                                    : xC + (size_t)(c8 - 4) * 32 * HWsz;
        s16x8 a;
        #pragma unroll
        for (int j = 0; j < 8; ++j)
            a[j] = (short)f2bf(src[(size_t)(cq * 8 + j) * HWsz + pix + p]);
        if (USE_WS) {
            const unsigned short* wb = w2 + WMAIN_ELEMS + (size_t)(c8 * 5) * 512;
            #pragma unroll
            for (int t = 0; t < 5; ++t) {
                s16x8 bf = *(const s16x8*)(wb + t * 512 + lane * 8);
                oa[t] = __builtin_amdgcn_mfma_f32_16x16x32_bf16(a, bf, oa[t], 0, 0, 0);
            }
        } else {
            #pragma unroll
            for (int t = 0; t < 5; ++t) {
                int o = t * 16 + p;
                s16x8 bf;
                #pragma unroll
                for (int j = 0; j < 8; ++j)
                    bf[j] = (o < 72) ? (short)f2bf(w_off[o * 256 + c8 * 32 + cq * 8 + j])
                                     : (short)0;
                oa[t] = __builtin_amdgcn_mfma_f32_16x16x32_bf16(a, bf, oa[t], 0, 0, 0);
            }
        }
    }
    // scatter D -> LDS: lane holds off[o = t*16+(lane&15)][px = cq*4+r]
    #pragma unroll
    for (int t = 0; t < 5; ++t) {
        int o = t * 16 + p;
        if (o < 72) {
            #pragma unroll
            for (int r = 0; r < 4; ++r)
                off_lds[wv][o * 16 + cq * 4 + r] = oa[t][r];
        }
    }
    // same-wave LDS RAW only (waves independent): compiler-inserted lgkmcnt.

    // ---- Phase B: 72 chunks, barrier-free ----
    f32x4 acc[8];
    #pragma unroll
    for (int t = 0; t < 8; ++t) { acc[t][0] = 0.f; acc[t][1] = 0.f; acc[t][2] = 0.f; acc[t][3] = 0.f; }

    for (int gkh = 0; gkh < 72; ++gkh) {
        const int half = gkh & 1, gk = gkh >> 1;
        const int k = gk % 9, g = gk / 9;
        const int ky = k / 3, kx = k % 3;

        float dy = off_lds[wv][(2 * gk) * 16 + p];
        float dx = off_lds[wv][(2 * gk + 1) * 16 + p];
        float fy = (float)(h - 1 + ky) + dy;
        float fx = (float)(ws_ * 16 + p - 1 + kx) + dx;
        float y0f = floorf(fy), x0f = floorf(fx);
        float wy = fy - y0f, wx = fx - x0f;
        int iy0 = (int)y0f, ix0 = (int)x0f;
        int iy1 = iy0 + 1, ix1 = ix0 + 1;
        float vy0 = (iy0 >= 0 && iy0 < H_) ? 1.f : 0.f;
        float vy1 = (iy1 >= 0 && iy1 < H_) ? 1.f : 0.f;
        float vx0 = (ix0 >= 0 && ix0 < W_) ? 1.f : 0.f;
        float vx1 = (ix1 >= 0 && ix1 < W_) ? 1.f : 0.f;
        float w00 = (1.f - wy) * (1.f - wx) * vy0 * vx0;
        float w01 = (1.f - wy) * wx * vy0 * vx1;
        float w10 = wy * (1.f - wx) * vy1 * vx0;
        float w11 = wy * wx * vy1 * vx1;
        int cy0 = min(max(iy0, 0), H_ - 1), cy1 = min(max(iy1, 0), H_ - 1);
        int cx0 = min(max(ix0, 0), W_ - 1), cx1 = min(max(ix1, 0), W_ - 1);
        int i00 = cy0 * W_ + cx0, i01 = cy0 * W_ + cx1;
        int i10 = cy1 * W_ + cx0, i11 = cy1 * W_ + cx1;

        const float* src = (g == 0) ? xA : (g == 1) ? xB
                         : (g == 2) ? xC : xC + (size_t)64 * HWsz;
        src += (size_t)(half * 32 + cq * 8) * HWsz;

        s16x8 a;
        #pragma unroll
        for (int pass = 0; pass < 2; ++pass) {
            const float* cp0 = src + (size_t)(pass * 4 + 0) * HWsz;
            const float* cp1 = src + (size_t)(pass * 4 + 1) * HWsz;
            const float* cp2 = src + (size_t)(pass * 4 + 2) * HWsz;
            const float* cp3 = src + (size_t)(pass * 4 + 3) * HWsz;
            float4 c0, c1, c2, c3;   // named regs: SROA-safe, no spill
            c0.x = cp0[i00]; c0.y = cp0[i01]; c0.z = cp0[i10]; c0.w = cp0[i11];
            c1.x = cp1[i00]; c1.y = cp1[i01]; c1.z = cp1[i10]; c1.w = cp1[i11];
            c2.x = cp2[i00]; c2.y = cp2[i01]; c2.z = cp2[i10]; c2.w = cp2[i11];
            c3.x = cp3[i00]; c3.y = cp3[i01]; c3.z = cp3[i10]; c3.w = cp3[i11];
            a[pass * 4 + 0] = (short)f2bf(fmaf(w00, c0.x, fmaf(w01, c0.y, fmaf(w10, c0.z, w11 * c0.w))));
            a[pass * 4 + 1] = (short)f2bf(fmaf(w00, c1.x, fmaf(w01, c1.y, fmaf(w10, c1.z, w11 * c1.w))));
            a[pass * 4 + 2] = (short)f2bf(fmaf(w00, c2.x, fmaf(w01, c2.y, fmaf(w10, c2.z, w11 * c2.w))));
            a[pass * 4 + 3] = (short)f2bf(fmaf(w00, c3.x, fmaf(w01, c3.y, fmaf(w10, c3.z, w11 * c3.w))));
        }

        if (USE_WS) {
            const unsigned short* wb = w2 + (size_t)gkh * 8192 + (size_t)nh * 8 * 512;
            #pragma unroll
            for (int t = 0; t < 8; ++t) {
                s16x8 bf = *(const s16x8*)(wb + t * 512 + lane * 8);
                acc[t] = __builtin_amdgcn_mfma_f32_16x16x32_bf16(a, bf, acc[t], 0, 0, 0);
            }
        } else {
            const int cbase = g * 64 + half * 32 + cq * 8;
            #pragma unroll
            for (int t = 0; t < 8; ++t) {
                int oc = nh * 128 + t * 16 + p;
                s16x8 bf;
                #pragma unroll
                for (int j = 0; j < 8; ++j)
                    bf[j] = (short)f2bf(w_def[(size_t)oc * 2304 + (size_t)(cbase + j) * 9 + k]);
                acc[t] = __builtin_amdgcn_mfma_f32_16x16x32_bf16(a, bf, acc[t], 0, 0, 0);
            }
        }
    }

    // ---- epilogue: ReLU + float4 stores ----
    const size_t obase = (size_t)b * OC_ * HWsz + (size_t)h * W_ + ws_ * 16 + cq * 4;
    #pragma unroll
    for (int t = 0; t < 8; ++t) {
        int oc = nh * 128 + t * 16 + p;
        float4 r;
        r.x = fmaxf(acc[t][0], 0.f);
        r.y = fmaxf(acc[t][1], 0.f);
        r.z = fmaxf(acc[t][2], 0.f);
        r.w = fmaxf(acc[t][3], 0.f);
        *(float4*)(out + obase + (size_t)oc * HWsz) = r;
    }
}

extern "C" void kernel_launch(void* const* d_in, const int* in_sizes, int n_in,
                              void* d_out, int out_size, void* d_ws, size_t ws_size,
                              hipStream_t stream) {
    const float* x0    = (const float*)d_in[0];
    const float* x1    = (const float*)d_in[1];
    const float* x2    = (const float*)d_in[2];
    const float* w_off = (const float*)d_in[3];
    const float* b_off = (const float*)d_in[4];
    const float* w_def = (const float*)d_in[5];
    float* out = (float*)d_out;
    unsigned short* w2 = (unsigned short*)d_ws;

    const size_t w2_bytes = (size_t)(WMAIN_ELEMS + WOFFB_ELEMS) * 2;   // 1.22 MB
    if (ws_size >= w2_bytes) {
        hipLaunchKernelGGL(wprep_kernel, dim3((WMAIN_ELEMS + WOFFB_ELEMS) / 256), dim3(256),
                           0, stream, w_def, w_off, w2);
        hipLaunchKernelGGL((deform_kernel<true>), dim3(2048), dim3(128), 0, stream,
                           x0, x1, x2, w_off, b_off, w_def, w2, out);
    } else {
        hipLaunchKernelGGL((deform_kernel<false>), dim3(2048), dim3(128), 0, stream,
                           x0, x1, x2, w_off, b_off, w_def, (const unsigned short*)nullptr, out);
    }
}

// Round 5
// 333.198 us; speedup vs baseline: 1.2350x; 1.2350x over previous
//
#include <hip/hip_runtime.h>

// Deformable conv fusion v5: v4 + XCD-locality swizzle + register-pipelined
// gather with pinned issue order.
// - 2048 blocks x 128 thr (2 independent waves: N-half 0/1 of one 16-px tile).
// - Swizzle: logical tile L -> XCD L/256, so each XCD's resident blocks span a
//   contiguous 16-row band of one batch (~4.7 MB) -> gathers are L2-hits.
// - Per chunk: combine(c0..c7) | issue B-frags | next geom + issue gathers |
//   8 MFMA. sched_barrier(0) pins boundaries so MFMA's vmcnt wait never
//   drains the in-flight gathers.

constexpr int H_ = 64, W_ = 256;
constexpr int HWsz = H_ * W_;
constexpr int OC_ = 256;
constexpr int WMAIN_ELEMS = 72 * 16 * 64 * 8;   // main-conv B frags
constexpr int WOFFB_ELEMS = 8 * 5 * 64 * 8;     // phase-A B frags

using f32x4 = __attribute__((ext_vector_type(4))) float;
using s16x8 = __attribute__((ext_vector_type(8))) short;

__device__ __forceinline__ unsigned short f2bf(float f) {
    unsigned u = __float_as_uint(f);
    return (unsigned short)((u + 0x7fffu + ((u >> 16) & 1u)) >> 16);
}

// w2 layout: [0, WMAIN): main frags [gkh 72][t 16][lane 64][j 8]
//   value = w_def[oc = t*16+(lane&15)][cin = g*64+half*32+(lane>>4)*8+j][k]
// [WMAIN, +WOFFB): phase-A frags [c8 8][t 5][lane 64][j 8]
__global__ __launch_bounds__(256) void wprep_kernel(const float* __restrict__ w_def,
                                                    const float* __restrict__ w_off,
                                                    unsigned short* __restrict__ w2) {
    int i = blockIdx.x * 256 + threadIdx.x;
    if (i < WMAIN_ELEMS) {
        int j = i & 7, lane = (i >> 3) & 63, t = (i >> 9) & 15, gkh = i >> 13;
        int half = gkh & 1, gk = gkh >> 1;
        int k = gk % 9, g = gk / 9;
        int oc = t * 16 + (lane & 15);
        int cin = g * 64 + half * 32 + (lane >> 4) * 8 + j;
        w2[i] = f2bf(w_def[(size_t)oc * 2304 + (size_t)cin * 9 + k]);
    } else if (i < WMAIN_ELEMS + WOFFB_ELEMS) {
        int i2 = i - WMAIN_ELEMS;
        int j = i2 & 7, lane = (i2 >> 3) & 63, idx = i2 >> 9;   // idx = c8*5 + t
        int t = idx % 5, c8 = idx / 5;
        int o = t * 16 + (lane & 15);
        int ch = c8 * 32 + (lane >> 4) * 8 + j;
        float v = (o < 72) ? w_off[o * 256 + ch] : 0.f;
        w2[i] = f2bf(v);
    }
}

struct Geom {
    float w00, w01, w10, w11;
    int o00, o01, o10, o11;      // per-lane int32 offsets (channel base folded in)
    const float* base;           // wave-uniform source base
};

__device__ __forceinline__ Geom make_geom(
    int gkh, const float* offp, int h, int wbase, int p, int cq,
    const float* xA, const float* xB, const float* xC)
{
    const int half = gkh & 1, gk = gkh >> 1;
    const int k = gk % 9, g = gk / 9;
    const int ky = k / 3, kx = k % 3;
    float dy = offp[(2 * gk) * 16 + p];
    float dx = offp[(2 * gk + 1) * 16 + p];
    float fy = (float)(h - 1 + ky) + dy;
    float fx = (float)(wbase + p - 1 + kx) + dx;
    float y0f = floorf(fy), x0f = floorf(fx);
    float wy = fy - y0f, wx = fx - x0f;
    int iy0 = (int)y0f, ix0 = (int)x0f;
    int iy1 = iy0 + 1, ix1 = ix0 + 1;
    float vy0 = (iy0 >= 0 && iy0 < H_) ? 1.f : 0.f;
    float vy1 = (iy1 >= 0 && iy1 < H_) ? 1.f : 0.f;
    float vx0 = (ix0 >= 0 && ix0 < W_) ? 1.f : 0.f;
    float vx1 = (ix1 >= 0 && ix1 < W_) ? 1.f : 0.f;
    Geom gm;
    gm.w00 = (1.f - wy) * (1.f - wx) * vy0 * vx0;
    gm.w01 = (1.f - wy) * wx * vy0 * vx1;
    gm.w10 = wy * (1.f - wx) * vy1 * vx0;
    gm.w11 = wy * wx * vy1 * vx1;
    int cy0 = min(max(iy0, 0), H_ - 1), cy1 = min(max(iy1, 0), H_ - 1);
    int cx0 = min(max(ix0, 0), W_ - 1), cx1 = min(max(ix1, 0), W_ - 1);
    int choff = (half * 32 + cq * 8) * HWsz;
    gm.o00 = choff + cy0 * W_ + cx0;
    gm.o01 = choff + cy0 * W_ + cx1;
    gm.o10 = choff + cy1 * W_ + cx0;
    gm.o11 = choff + cy1 * W_ + cx1;
    gm.base = (g == 0) ? xA : (g == 1) ? xB : (g == 2) ? xC : xC + (size_t)64 * HWsz;
    return gm;
}

#define GATHER(J, C) do { \
    C.x = gm.base[gm.o00 + (J) * HWsz]; \
    C.y = gm.base[gm.o01 + (J) * HWsz]; \
    C.z = gm.base[gm.o10 + (J) * HWsz]; \
    C.w = gm.base[gm.o11 + (J) * HWsz]; \
} while (0)

#define COMB(C, IDX) \
    a[IDX] = (short)f2bf(fmaf(w00c, C.x, fmaf(w01c, C.y, fmaf(w10c, C.z, w11c * C.w))))

template<bool USE_WS>
__global__ __launch_bounds__(128, 3) void deform_kernel(
    const float* __restrict__ x0, const float* __restrict__ x1,
    const float* __restrict__ x2,
    const float* __restrict__ w_off, const float* __restrict__ b_off,
    const float* __restrict__ w_def, const unsigned short* __restrict__ w2,
    float* __restrict__ out)
{
    __shared__ float off_lds[2][72 * 16];   // per-wave offset tiles (9.2 KB)

    const int tid  = threadIdx.x;
    const int lane = tid & 63;
    const int wv   = tid >> 6;
    // XCD-locality swizzle: logical tile bid -> XCD bid/256 (grid 2048 = 8*256)
    const int bid  = ((blockIdx.x & 7) << 8) | (blockIdx.x >> 3);
    const int nh   = wv;                    // N-half: oc base = nh*128
    const int ws_  = bid & 15;
    const int h    = (bid >> 4) & 63;
    const int b    = bid >> 10;
    const int p    = lane & 15;             // this lane's pixel (A row)
    const int cq   = lane >> 4;             // channel quad
    const int wbase = ws_ * 16;
    const int pix  = h * W_ + wbase;

    const float* xA = x0 + (size_t)b * 64  * HWsz;
    const float* xB = x1 + (size_t)b * 64  * HWsz;
    const float* xC = x2 + (size_t)b * 128 * HWsz;

    // ---- Phase A: offsets via MFMA (16px x 256ch) @ (256ch x 80off) ----
    f32x4 oa[5];
    #pragma unroll
    for (int t = 0; t < 5; ++t) {
        int o = t * 16 + p;
        float bv = (o < 72) ? b_off[o] : 0.f;
        oa[t][0] = bv; oa[t][1] = bv; oa[t][2] = bv; oa[t][3] = bv;
    }
    #pragma unroll
    for (int c8 = 0; c8 < 8; ++c8) {
        const float* src = (c8 < 2) ? xA + (size_t)c8 * 32 * HWsz
                         : (c8 < 4) ? xB + (size_t)(c8 - 2) * 32 * HWsz
                                    : xC + (size_t)(c8 - 4) * 32 * HWsz;
        s16x8 a;
        #pragma unroll
        for (int j = 0; j < 8; ++j)
            a[j] = (short)f2bf(src[(cq * 8 + j) * HWsz + pix + p]);
        if (USE_WS) {
            const unsigned short* wb = w2 + WMAIN_ELEMS + (size_t)(c8 * 5) * 512;
            #pragma unroll
            for (int t = 0; t < 5; ++t) {
                s16x8 bf = *(const s16x8*)(wb + t * 512 + lane * 8);
                oa[t] = __builtin_amdgcn_mfma_f32_16x16x32_bf16(a, bf, oa[t], 0, 0, 0);
            }
        } else {
            #pragma unroll
            for (int t = 0; t < 5; ++t) {
                int o = t * 16 + p;
                s16x8 bf;
                #pragma unroll
                for (int j = 0; j < 8; ++j)
                    bf[j] = (o < 72) ? (short)f2bf(w_off[o * 256 + c8 * 32 + cq * 8 + j])
                                     : (short)0;
                oa[t] = __builtin_amdgcn_mfma_f32_16x16x32_bf16(a, bf, oa[t], 0, 0, 0);
            }
        }
    }
    #pragma unroll
    for (int t = 0; t < 5; ++t) {
        int o = t * 16 + p;
        if (o < 72) {
            #pragma unroll
            for (int r = 0; r < 4; ++r)
                off_lds[wv][o * 16 + cq * 4 + r] = oa[t][r];
        }
    }
    // same-wave LDS RAW only; compiler inserts lgkmcnt.

    // ---- Phase B: pipelined gather + MFMA, 72 chunks, barrier-free ----
    f32x4 acc0 = {0,0,0,0}, acc1 = {0,0,0,0}, acc2 = {0,0,0,0}, acc3 = {0,0,0,0};
    f32x4 acc4 = {0,0,0,0}, acc5 = {0,0,0,0}, acc6 = {0,0,0,0}, acc7 = {0,0,0,0};

    const float* offp = &off_lds[wv][0];

    if (USE_WS) {
        Geom gm = make_geom(0, offp, h, wbase, p, cq, xA, xB, xC);
        float4 c0, c1, c2, c3, c4, c5, c6, c7;
        GATHER(0, c0); GATHER(1, c1); GATHER(2, c2); GATHER(3, c3);
        GATHER(4, c4); GATHER(5, c5); GATHER(6, c6); GATHER(7, c7);

        for (int gkh = 0; gkh < 72; ++gkh) {
            // 1) combine this chunk's corners -> A frag (waits on gathers)
            float w00c = gm.w00, w01c = gm.w01, w10c = gm.w10, w11c = gm.w11;
            s16x8 a;
            COMB(c0, 0); COMB(c1, 1); COMB(c2, 2); COMB(c3, 3);
            COMB(c4, 4); COMB(c5, 5); COMB(c6, 6); COMB(c7, 7);
            __builtin_amdgcn_sched_barrier(0);

            // 2) issue B-frag loads FIRST (so MFMA's wait excludes the gathers)
            const unsigned short* wb = w2 + gkh * 8192 + nh * 4096 + lane * 8;
            s16x8 b0 = *(const s16x8*)(wb + 0 * 512);
            s16x8 b1 = *(const s16x8*)(wb + 1 * 512);
            s16x8 b2 = *(const s16x8*)(wb + 2 * 512);
            s16x8 b3 = *(const s16x8*)(wb + 3 * 512);
            s16x8 b4 = *(const s16x8*)(wb + 4 * 512);
            s16x8 b5 = *(const s16x8*)(wb + 5 * 512);
            s16x8 b6 = *(const s16x8*)(wb + 6 * 512);
            s16x8 b7 = *(const s16x8*)(wb + 7 * 512);
            __builtin_amdgcn_sched_barrier(0);

            // 3) next chunk's geometry + gather issue (in flight across MFMAs)
            if (gkh + 1 < 72) {
                gm = make_geom(gkh + 1, offp, h, wbase, p, cq, xA, xB, xC);
                GATHER(0, c0); GATHER(1, c1); GATHER(2, c2); GATHER(3, c3);
                GATHER(4, c4); GATHER(5, c5); GATHER(6, c6); GATHER(7, c7);
            }
            __builtin_amdgcn_sched_barrier(0);

            // 4) MFMAs (vmcnt wait covers only the older B-loads)
            acc0 = __builtin_amdgcn_mfma_f32_16x16x32_bf16(a, b0, acc0, 0, 0, 0);
            acc1 = __builtin_amdgcn_mfma_f32_16x16x32_bf16(a, b1, acc1, 0, 0, 0);
            acc2 = __builtin_amdgcn_mfma_f32_16x16x32_bf16(a, b2, acc2, 0, 0, 0);
            acc3 = __builtin_amdgcn_mfma_f32_16x16x32_bf16(a, b3, acc3, 0, 0, 0);
            acc4 = __builtin_amdgcn_mfma_f32_16x16x32_bf16(a, b4, acc4, 0, 0, 0);
            acc5 = __builtin_amdgcn_mfma_f32_16x16x32_bf16(a, b5, acc5, 0, 0, 0);
            acc6 = __builtin_amdgcn_mfma_f32_16x16x32_bf16(a, b6, acc6, 0, 0, 0);
            acc7 = __builtin_amdgcn_mfma_f32_16x16x32_bf16(a, b7, acc7, 0, 0, 0);
        }
    } else {
        // correctness fallback (unpipelined), used only if d_ws is too small
        for (int gkh = 0; gkh < 72; ++gkh) {
            Geom gm = make_geom(gkh, offp, h, wbase, p, cq, xA, xB, xC);
            float4 c0, c1, c2, c3, c4, c5, c6, c7;
            GATHER(0, c0); GATHER(1, c1); GATHER(2, c2); GATHER(3, c3);
            GATHER(4, c4); GATHER(5, c5); GATHER(6, c6); GATHER(7, c7);
            float w00c = gm.w00, w01c = gm.w01, w10c = gm.w10, w11c = gm.w11;
            s16x8 a;
            COMB(c0, 0); COMB(c1, 1); COMB(c2, 2); COMB(c3, 3);
            COMB(c4, 4); COMB(c5, 5); COMB(c6, 6); COMB(c7, 7);
            const int half = gkh & 1, gk = gkh >> 1;
            const int k = gk % 9, g = gk / 9;
            const int cbase = g * 64 + half * 32 + cq * 8;
            f32x4* accp[8] = {&acc0,&acc1,&acc2,&acc3,&acc4,&acc5,&acc6,&acc7};
            #pragma unroll
            for (int t = 0; t < 8; ++t) {
                int oc = nh * 128 + t * 16 + p;
                s16x8 bf;
                #pragma unroll
                for (int j = 0; j < 8; ++j)
                    bf[j] = (short)f2bf(w_def[(size_t)oc * 2304 + (size_t)(cbase + j) * 9 + k]);
                *accp[t] = __builtin_amdgcn_mfma_f32_16x16x32_bf16(a, bf, *accp[t], 0, 0, 0);
            }
        }
    }

    // ---- epilogue: ReLU + float4 stores ----
    const size_t obase = (size_t)b * OC_ * HWsz + (size_t)h * W_ + wbase + cq * 4;
    f32x4 accs[8] = {acc0, acc1, acc2, acc3, acc4, acc5, acc6, acc7};
    #pragma unroll
    for (int t = 0; t < 8; ++t) {
        int oc = nh * 128 + t * 16 + p;
        float4 r;
        r.x = fmaxf(accs[t][0], 0.f);
        r.y = fmaxf(accs[t][1], 0.f);
        r.z = fmaxf(accs[t][2], 0.f);
        r.w = fmaxf(accs[t][3], 0.f);
        *(float4*)(out + obase + (size_t)oc * HWsz) = r;
    }
}

extern "C" void kernel_launch(void* const* d_in, const int* in_sizes, int n_in,
                              void* d_out, int out_size, void* d_ws, size_t ws_size,
                              hipStream_t stream) {
    const float* x0    = (const float*)d_in[0];
    const float* x1    = (const float*)d_in[1];
    const float* x2    = (const float*)d_in[2];
    const float* w_off = (const float*)d_in[3];
    const float* b_off = (const float*)d_in[4];
    const float* w_def = (const float*)d_in[5];
    float* out = (float*)d_out;
    unsigned short* w2 = (unsigned short*)d_ws;

    const size_t w2_bytes = (size_t)(WMAIN_ELEMS + WOFFB_ELEMS) * 2;   // 1.22 MB
    if (ws_size >= w2_bytes) {
        hipLaunchKernelGGL(wprep_kernel, dim3((WMAIN_ELEMS + WOFFB_ELEMS) / 256), dim3(256),
                           0, stream, w_def, w_off, w2);
        hipLaunchKernelGGL((deform_kernel<true>), dim3(2048), dim3(128), 0, stream,
                           x0, x1, x2, w_off, b_off, w_def, w2, out);
    } else {
        hipLaunchKernelGGL((deform_kernel<false>), dim3(2048), dim3(128), 0, stream,
                           x0, x1, x2, w_off, b_off, w_def, (const unsigned short*)nullptr, out);
    }
}

// Round 6
// 183.753 us; speedup vs baseline: 2.2395x; 1.8133x over previous
//
#include <hip/hip_runtime.h>

// Deformable conv fusion v6: NHWC-bf16 repacked x + 32px x 128oc waves.
// - xprep: transpose x (NCHW f32) -> xt[b*4+g][y][x][c64] bf16. One pixel's
//   8 chunk-channels = one 16B dwordx4 -> gather transactions collapse ~6x.
// - deform32: 1024 blocks x 128 thr; wave = 32px x 128oc (two 16x16x32
//   A-frags share each B-frag -> B traffic per pixel halved). Barrier-free,
//   XCD-swizzled, corners + B prefetched one chunk ahead (ping-pong B).
// - Tiered fallback: w2-only -> v5 kernel; no ws -> direct slow path.

constexpr int H_ = 64, W_ = 256;
constexpr int HWsz = H_ * W_;
constexpr int OC_ = 256;
constexpr int WMAIN_ELEMS = 72 * 16 * 64 * 8;
constexpr int WOFFB_ELEMS = 8 * 5 * 64 * 8;
constexpr size_t XT_ELEMS = (size_t)8 * HWsz * 64;   // [bg 8][y][x][c 64] bf16

using f32x4 = __attribute__((ext_vector_type(4))) float;
using s16x8 = __attribute__((ext_vector_type(8))) short;
using u16x8 = __attribute__((ext_vector_type(8))) unsigned short;

__device__ __forceinline__ unsigned short f2bf(float f) {
    unsigned u = __float_as_uint(f);
    return (unsigned short)((u + 0x7fffu + ((u >> 16) & 1u)) >> 16);
}
__device__ __forceinline__ float bf2f(unsigned short u) {
    return __uint_as_float((unsigned)u << 16);
}

// ---------------- prep kernels ----------------

// w2 layout: [0, WMAIN): main frags [gkh 72][t 16][lane 64][j 8]
//   value = w_def[oc = t*16+(lane&15)][cin = g*64+half*32+(lane>>4)*8+j][k]
// [WMAIN, +WOFFB): phase-A frags [c8 8][t 5][lane 64][j 8]
__global__ __launch_bounds__(256) void wprep_kernel(const float* __restrict__ w_def,
                                                    const float* __restrict__ w_off,
                                                    unsigned short* __restrict__ w2) {
    int i = blockIdx.x * 256 + threadIdx.x;
    if (i < WMAIN_ELEMS) {
        int j = i & 7, lane = (i >> 3) & 63, t = (i >> 9) & 15, gkh = i >> 13;
        int half = gkh & 1, gk = gkh >> 1;
        int k = gk % 9, g = gk / 9;
        int oc = t * 16 + (lane & 15);
        int cin = g * 64 + half * 32 + (lane >> 4) * 8 + j;
        w2[i] = f2bf(w_def[(size_t)oc * 2304 + (size_t)cin * 9 + k]);
    } else if (i < WMAIN_ELEMS + WOFFB_ELEMS) {
        int i2 = i - WMAIN_ELEMS;
        int j = i2 & 7, lane = (i2 >> 3) & 63, idx = i2 >> 9;   // idx = c8*5 + t
        int t = idx % 5, c8 = idx / 5;
        int o = t * 16 + (lane & 15);
        int ch = c8 * 32 + (lane >> 4) * 8 + j;
        float v = (o < 72) ? w_off[o * 256 + ch] : 0.f;
        w2[i] = f2bf(v);
    }
}

// xt[bg][y][x][c]: block = (bg, y); read 64ch x 256px coalesced, LDS
// transpose, write contiguous 32KB.
__global__ __launch_bounds__(256) void xprep_kernel(const float* __restrict__ x0,
                                                    const float* __restrict__ x1,
                                                    const float* __restrict__ x2,
                                                    unsigned short* __restrict__ xt) {
    __shared__ unsigned short tl[256][66];
    const int bg = blockIdx.x >> 6;
    const int y  = blockIdx.x & 63;
    const int b  = bg >> 2, g = bg & 3;
    const int tid = threadIdx.x;
    const float* src = (g == 0) ? x0 + (size_t)b * 64 * HWsz
                     : (g == 1) ? x1 + (size_t)b * 64 * HWsz
                     : x2 + (size_t)b * 128 * HWsz + (size_t)(g - 2) * 64 * HWsz;
    src += y * W_;
    for (int c = 0; c < 64; ++c)
        tl[tid][c] = f2bf(src[(size_t)c * HWsz + tid]);
    __syncthreads();
    unsigned short* dst = xt + ((size_t)bg * HWsz + y * W_) * 64;
    #pragma unroll
    for (int s = 0; s < 8; ++s) {
        int si = s * 256 + tid;           // 16B store units, fully contiguous
        int px = si >> 3, q = si & 7;
        u16x8 v;
        #pragma unroll
        for (int j = 0; j < 8; ++j) v[j] = tl[px][q * 8 + j];
        *(u16x8*)(dst + (size_t)px * 64 + q * 8) = v;
    }
}

// ---------------- main kernel (tier 2) ----------------

struct GeomT {
    float w00, w01, w10, w11;
    int o00, o01, o10, o11;              // ushort offsets in (b,g) plane
    const unsigned short* base;
};

__device__ __forceinline__ GeomT make_geomT(
    int gkh, const float* offp, int h, int xcoord, int pgp, int cq,
    const unsigned short* xtb)
{
    const int half = gkh & 1, gk = gkh >> 1;
    const int k = gk % 9, g = gk / 9;
    const int ky = k / 3, kx = k % 3;
    float dy = offp[(2 * gk) * 32 + pgp];
    float dx = offp[(2 * gk + 1) * 32 + pgp];
    float fy = (float)(h - 1 + ky) + dy;
    float fx = (float)(xcoord - 1 + kx) + dx;
    float y0f = floorf(fy), x0f = floorf(fx);
    float wy = fy - y0f, wx = fx - x0f;
    int iy0 = (int)y0f, ix0 = (int)x0f;
    int iy1 = iy0 + 1, ix1 = ix0 + 1;
    float vy0 = (iy0 >= 0 && iy0 < H_) ? 1.f : 0.f;
    float vy1 = (iy1 >= 0 && iy1 < H_) ? 1.f : 0.f;
    float vx0 = (ix0 >= 0 && ix0 < W_) ? 1.f : 0.f;
    float vx1 = (ix1 >= 0 && ix1 < W_) ? 1.f : 0.f;
    GeomT gm;
    gm.w00 = (1.f - wy) * (1.f - wx) * vy0 * vx0;
    gm.w01 = (1.f - wy) * wx * vy0 * vx1;
    gm.w10 = wy * (1.f - wx) * vy1 * vx0;
    gm.w11 = wy * wx * vy1 * vx1;
    int cy0 = min(max(iy0, 0), H_ - 1), cy1 = min(max(iy1, 0), H_ - 1);
    int cx0 = min(max(ix0, 0), W_ - 1), cx1 = min(max(ix1, 0), W_ - 1);
    int ch = half * 32 + cq * 8;
    gm.o00 = (cy0 * W_ + cx0) * 64 + ch;
    gm.o01 = (cy0 * W_ + cx1) * 64 + ch;
    gm.o10 = (cy1 * W_ + cx0) * 64 + ch;
    gm.o11 = (cy1 * W_ + cx1) * 64 + ch;
    gm.base = xtb + (size_t)g * HWsz * 64;
    return gm;
}

__device__ __forceinline__ void load_corners(const GeomT& g0, const GeomT& g1,
                                             u16x8 (&C)[8]) {
    C[0] = *(const u16x8*)(g0.base + g0.o00);
    C[1] = *(const u16x8*)(g0.base + g0.o01);
    C[2] = *(const u16x8*)(g0.base + g0.o10);
    C[3] = *(const u16x8*)(g0.base + g0.o11);
    C[4] = *(const u16x8*)(g1.base + g1.o00);
    C[5] = *(const u16x8*)(g1.base + g1.o01);
    C[6] = *(const u16x8*)(g1.base + g1.o10);
    C[7] = *(const u16x8*)(g1.base + g1.o11);
}

__device__ __forceinline__ s16x8 combine4(const u16x8& c00, const u16x8& c01,
                                          const u16x8& c10, const u16x8& c11,
                                          float w00, float w01, float w10, float w11) {
    s16x8 a;
    #pragma unroll
    for (int j = 0; j < 8; ++j) {
        float v = fmaf(w00, bf2f(c00[j]), fmaf(w01, bf2f(c01[j]),
                  fmaf(w10, bf2f(c10[j]), w11 * bf2f(c11[j]))));
        a[j] = (short)f2bf(v);
    }
    return a;
}

__device__ __forceinline__ void load_bfrag(const unsigned short* w2c, s16x8 (&B)[8]) {
    #pragma unroll
    for (int t = 0; t < 8; ++t) B[t] = *(const s16x8*)(w2c + t * 512);
}

__device__ __forceinline__ void mfma8(const s16x8& a, const s16x8 (&B)[8],
                                      f32x4 (&acc)[8]) {
    #pragma unroll
    for (int t = 0; t < 8; ++t)
        acc[t] = __builtin_amdgcn_mfma_f32_16x16x32_bf16(a, B[t], acc[t], 0, 0, 0);
}

__global__ __launch_bounds__(128, 2) void deform32_kernel(
    const unsigned short* __restrict__ xt, const float* __restrict__ b_off,
    const unsigned short* __restrict__ w2, float* __restrict__ out)
{
    __shared__ float off_lds[2][72 * 32];   // 18.4 KB

    const int tid  = threadIdx.x;
    const int lane = tid & 63;
    const int wv   = tid >> 6;
    // XCD swizzle: 1024 = 8 * 128 -> each XCD gets a contiguous 16-row band
    const int bid  = ((blockIdx.x & 7) << 7) | (blockIdx.x >> 3);
    const int nh   = wv;                    // oc base = nh*128
    const int xq   = bid & 7;               // 32-px x tile
    const int h    = (bid >> 3) & 63;
    const int b    = bid >> 9;
    const int p16  = lane & 15;
    const int cq   = lane >> 4;
    const int wbase = xq * 32;

    const unsigned short* xtb = xt + (size_t)b * 4 * HWsz * 64;

    // ---- Phase A: offsets via MFMA, two 16-px groups ----
    for (int pg = 0; pg < 2; ++pg) {
        f32x4 oa[5];
        #pragma unroll
        for (int t = 0; t < 5; ++t) {
            int o = t * 16 + p16;
            float bv = (o < 72) ? b_off[o] : 0.f;
            oa[t][0] = bv; oa[t][1] = bv; oa[t][2] = bv; oa[t][3] = bv;
        }
        const int pixg = h * W_ + wbase + pg * 16;
        #pragma unroll
        for (int c8 = 0; c8 < 8; ++c8) {
            const unsigned short* ap = xtb + (size_t)(c8 >> 1) * HWsz * 64
                                     + (size_t)(pixg + p16) * 64 + (c8 & 1) * 32 + cq * 8;
            s16x8 a = *(const s16x8*)ap;
            const unsigned short* wb = w2 + WMAIN_ELEMS + (size_t)(c8 * 5) * 512;
            #pragma unroll
            for (int t = 0; t < 5; ++t) {
                s16x8 bf = *(const s16x8*)(wb + t * 512 + lane * 8);
                oa[t] = __builtin_amdgcn_mfma_f32_16x16x32_bf16(a, bf, oa[t], 0, 0, 0);
            }
        }
        #pragma unroll
        for (int t = 0; t < 5; ++t) {
            int o = t * 16 + p16;
            if (o < 72) {
                #pragma unroll
                for (int r = 0; r < 4; ++r)
                    off_lds[wv][o * 32 + pg * 16 + cq * 4 + r] = oa[t][r];
            }
        }
    }
    // same-wave LDS RAW only (waves independent) -> compiler lgkmcnt.

    // ---- Phase B: 72 chunks, ping-pong B, corners prefetched 1 ahead ----
    f32x4 accP[8], accQ[8];
    #pragma unroll
    for (int t = 0; t < 8; ++t) {
        accP[t][0]=0;accP[t][1]=0;accP[t][2]=0;accP[t][3]=0;
        accQ[t][0]=0;accQ[t][1]=0;accQ[t][2]=0;accQ[t][3]=0;
    }

    const float* offp = &off_lds[wv][0];
    const int xc0 = wbase + p16, xc1 = wbase + 16 + p16;
    const unsigned short* w2m = w2 + nh * 4096 + lane * 8;

    GeomT gm0 = make_geomT(0, offp, h, xc0, p16, cq, xtb);
    GeomT gm1 = make_geomT(0, offp, h, xc1, 16 + p16, cq, xtb);
    u16x8 C[8];
    s16x8 Ba[8], Bb[8];
    load_corners(gm0, gm1, C);
    load_bfrag(w2m, Ba);

    for (int it = 0; it < 36; ++it) {
        {   // chunk 2*it : use Ba, prefetch chunk 2*it+1 into Bb
            s16x8 a0 = combine4(C[0], C[1], C[2], C[3], gm0.w00, gm0.w01, gm0.w10, gm0.w11);
            s16x8 a1 = combine4(C[4], C[5], C[6], C[7], gm1.w00, gm1.w01, gm1.w10, gm1.w11);
            __builtin_amdgcn_sched_barrier(0);
            const int gn = 2 * it + 1;
            gm0 = make_geomT(gn, offp, h, xc0, p16, cq, xtb);
            gm1 = make_geomT(gn, offp, h, xc1, 16 + p16, cq, xtb);
            load_corners(gm0, gm1, C);
            load_bfrag(w2m + gn * 8192, Bb);
            __builtin_amdgcn_sched_barrier(0);
            mfma8(a0, Ba, accP);
            mfma8(a1, Ba, accQ);
        }
        {   // chunk 2*it+1 : use Bb, prefetch next into Ba
            s16x8 a0 = combine4(C[0], C[1], C[2], C[3], gm0.w00, gm0.w01, gm0.w10, gm0.w11);
            s16x8 a1 = combine4(C[4], C[5], C[6], C[7], gm1.w00, gm1.w01, gm1.w10, gm1.w11);
            __builtin_amdgcn_sched_barrier(0);
            const int gn = (2 * it + 2 < 72) ? 2 * it + 2 : 71;   // tail: redundant reload
            gm0 = make_geomT(gn, offp, h, xc0, p16, cq, xtb);
            gm1 = make_geomT(gn, offp, h, xc1, 16 + p16, cq, xtb);
            load_corners(gm0, gm1, C);
            load_bfrag(w2m + gn * 8192, Ba);
            __builtin_amdgcn_sched_barrier(0);
            mfma8(a0, Bb, accP);
            mfma8(a1, Bb, accQ);
        }
    }

    // ---- epilogue: ReLU + float4 stores ----
    const size_t obase = (size_t)b * OC_ * HWsz + (size_t)h * W_ + wbase + cq * 4;
    #pragma unroll
    for (int t = 0; t < 8; ++t) {
        int oc = nh * 128 + t * 16 + p16;
        float4 r0, r1;
        r0.x = fmaxf(accP[t][0], 0.f); r0.y = fmaxf(accP[t][1], 0.f);
        r0.z = fmaxf(accP[t][2], 0.f); r0.w = fmaxf(accP[t][3], 0.f);
        r1.x = fmaxf(accQ[t][0], 0.f); r1.y = fmaxf(accQ[t][1], 0.f);
        r1.z = fmaxf(accQ[t][2], 0.f); r1.w = fmaxf(accQ[t][3], 0.f);
        *(float4*)(out + obase + (size_t)oc * HWsz) = r0;
        *(float4*)(out + obase + (size_t)oc * HWsz + 16) = r1;
    }
}

// ---------------- tier-1/0 fallback (v5 kernel, verified) ----------------

struct Geom {
    float w00, w01, w10, w11;
    int o00, o01, o10, o11;
    const float* base;
};

__device__ __forceinline__ Geom make_geom(
    int gkh, const float* offp, int h, int wbase, int p, int cq,
    const float* xA, const float* xB, const float* xC)
{
    const int half = gkh & 1, gk = gkh >> 1;
    const int k = gk % 9, g = gk / 9;
    const int ky = k / 3, kx = k % 3;
    float dy = offp[(2 * gk) * 16 + p];
    float dx = offp[(2 * gk + 1) * 16 + p];
    float fy = (float)(h - 1 + ky) + dy;
    float fx = (float)(wbase + p - 1 + kx) + dx;
    float y0f = floorf(fy), x0f = floorf(fx);
    float wy = fy - y0f, wx = fx - x0f;
    int iy0 = (int)y0f, ix0 = (int)x0f;
    int iy1 = iy0 + 1, ix1 = ix0 + 1;
    float vy0 = (iy0 >= 0 && iy0 < H_) ? 1.f : 0.f;
    float vy1 = (iy1 >= 0 && iy1 < H_) ? 1.f : 0.f;
    float vx0 = (ix0 >= 0 && ix0 < W_) ? 1.f : 0.f;
    float vx1 = (ix1 >= 0 && ix1 < W_) ? 1.f : 0.f;
    Geom gm;
    gm.w00 = (1.f - wy) * (1.f - wx) * vy0 * vx0;
    gm.w01 = (1.f - wy) * wx * vy0 * vx1;
    gm.w10 = wy * (1.f - wx) * vy1 * vx0;
    gm.w11 = wy * wx * vy1 * vx1;
    int cy0 = min(max(iy0, 0), H_ - 1), cy1 = min(max(iy1, 0), H_ - 1);
    int cx0 = min(max(ix0, 0), W_ - 1), cx1 = min(max(ix1, 0), W_ - 1);
    int choff = (half * 32 + cq * 8) * HWsz;
    gm.o00 = choff + cy0 * W_ + cx0;
    gm.o01 = choff + cy0 * W_ + cx1;
    gm.o10 = choff + cy1 * W_ + cx0;
    gm.o11 = choff + cy1 * W_ + cx1;
    gm.base = (g == 0) ? xA : (g == 1) ? xB : (g == 2) ? xC : xC + (size_t)64 * HWsz;
    return gm;
}

#define GATHER(J, Cv) do { \
    Cv.x = gm.base[gm.o00 + (J) * HWsz]; \
    Cv.y = gm.base[gm.o01 + (J) * HWsz]; \
    Cv.z = gm.base[gm.o10 + (J) * HWsz]; \
    Cv.w = gm.base[gm.o11 + (J) * HWsz]; \
} while (0)

#define COMB(Cv, IDX) \
    a[IDX] = (short)f2bf(fmaf(w00c, Cv.x, fmaf(w01c, Cv.y, fmaf(w10c, Cv.z, w11c * Cv.w))))

template<bool USE_WS>
__global__ __launch_bounds__(128, 3) void deform_kernel(
    const float* __restrict__ x0, const float* __restrict__ x1,
    const float* __restrict__ x2,
    const float* __restrict__ w_off, const float* __restrict__ b_off,
    const float* __restrict__ w_def, const unsigned short* __restrict__ w2,
    float* __restrict__ out)
{
    __shared__ float off_lds[2][72 * 16];

    const int tid  = threadIdx.x;
    const int lane = tid & 63;
    const int wv   = tid >> 6;
    const int bid  = ((blockIdx.x & 7) << 8) | (blockIdx.x >> 3);
    const int nh   = wv;
    const int ws_  = bid & 15;
    const int h    = (bid >> 4) & 63;
    const int b    = bid >> 10;
    const int p    = lane & 15;
    const int cq   = lane >> 4;
    const int wbase = ws_ * 16;
    const int pix  = h * W_ + wbase;

    const float* xA = x0 + (size_t)b * 64  * HWsz;
    const float* xB = x1 + (size_t)b * 64  * HWsz;
    const float* xC = x2 + (size_t)b * 128 * HWsz;

    f32x4 oa[5];
    #pragma unroll
    for (int t = 0; t < 5; ++t) {
        int o = t * 16 + p;
        float bv = (o < 72) ? b_off[o] : 0.f;
        oa[t][0] = bv; oa[t][1] = bv; oa[t][2] = bv; oa[t][3] = bv;
    }
    #pragma unroll
    for (int c8 = 0; c8 < 8; ++c8) {
        const float* src = (c8 < 2) ? xA + (size_t)c8 * 32 * HWsz
                         : (c8 < 4) ? xB + (size_t)(c8 - 2) * 32 * HWsz
                                    : xC + (size_t)(c8 - 4) * 32 * HWsz;
        s16x8 a;
        #pragma unroll
        for (int j = 0; j < 8; ++j)
            a[j] = (short)f2bf(src[(cq * 8 + j) * HWsz + pix + p]);
        #pragma unroll
        for (int t = 0; t < 5; ++t) {
            int o = t * 16 + p;
            s16x8 bf;
            if (USE_WS) {
                bf = *(const s16x8*)(w2 + WMAIN_ELEMS + (size_t)(c8 * 5 + t) * 512 + lane * 8);
            } else {
                #pragma unroll
                for (int j = 0; j < 8; ++j)
                    bf[j] = (o < 72) ? (short)f2bf(w_off[o * 256 + c8 * 32 + cq * 8 + j])
                                     : (short)0;
            }
            oa[t] = __builtin_amdgcn_mfma_f32_16x16x32_bf16(a, bf, oa[t], 0, 0, 0);
        }
    }
    #pragma unroll
    for (int t = 0; t < 5; ++t) {
        int o = t * 16 + p;
        if (o < 72) {
            #pragma unroll
            for (int r = 0; r < 4; ++r)
                off_lds[wv][o * 16 + cq * 4 + r] = oa[t][r];
        }
    }

    f32x4 acc0={0,0,0,0},acc1={0,0,0,0},acc2={0,0,0,0},acc3={0,0,0,0};
    f32x4 acc4={0,0,0,0},acc5={0,0,0,0},acc6={0,0,0,0},acc7={0,0,0,0};
    const float* offp = &off_lds[wv][0];

    for (int gkh = 0; gkh < 72; ++gkh) {
        Geom gm = make_geom(gkh, offp, h, wbase, p, cq, xA, xB, xC);
        float4 c0, c1, c2, c3, c4, c5, c6, c7;
        GATHER(0, c0); GATHER(1, c1); GATHER(2, c2); GATHER(3, c3);
        GATHER(4, c4); GATHER(5, c5); GATHER(6, c6); GATHER(7, c7);
        float w00c = gm.w00, w01c = gm.w01, w10c = gm.w10, w11c = gm.w11;
        s16x8 a;
        COMB(c0, 0); COMB(c1, 1); COMB(c2, 2); COMB(c3, 3);
        COMB(c4, 4); COMB(c5, 5); COMB(c6, 6); COMB(c7, 7);
        const int half = gkh & 1, gk = gkh >> 1;
        const int k = gk % 9, g = gk / 9;
        const int cbase = g * 64 + half * 32 + cq * 8;
        f32x4* accp[8] = {&acc0,&acc1,&acc2,&acc3,&acc4,&acc5,&acc6,&acc7};
        #pragma unroll
        for (int t = 0; t < 8; ++t) {
            int oc = nh * 128 + t * 16 + p;
            s16x8 bf;
            if (USE_WS) {
                bf = *(const s16x8*)(w2 + gkh * 8192 + nh * 4096 + t * 512 + lane * 8);
            } else {
                #pragma unroll
                for (int j = 0; j < 8; ++j)
                    bf[j] = (short)f2bf(w_def[(size_t)oc * 2304 + (size_t)(cbase + j) * 9 + k]);
            }
            *accp[t] = __builtin_amdgcn_mfma_f32_16x16x32_bf16(a, bf, *accp[t], 0, 0, 0);
        }
    }

    const size_t obase = (size_t)b * OC_ * HWsz + (size_t)h * W_ + wbase + cq * 4;
    f32x4 accs[8] = {acc0, acc1, acc2, acc3, acc4, acc5, acc6, acc7};
    #pragma unroll
    for (int t = 0; t < 8; ++t) {
        int oc = nh * 128 + t * 16 + p;
        float4 r;
        r.x = fmaxf(accs[t][0], 0.f);
        r.y = fmaxf(accs[t][1], 0.f);
        r.z = fmaxf(accs[t][2], 0.f);
        r.w = fmaxf(accs[t][3], 0.f);
        *(float4*)(out + obase + (size_t)oc * HWsz) = r;
    }
}

extern "C" void kernel_launch(void* const* d_in, const int* in_sizes, int n_in,
                              void* d_out, int out_size, void* d_ws, size_t ws_size,
                              hipStream_t stream) {
    const float* x0    = (const float*)d_in[0];
    const float* x1    = (const float*)d_in[1];
    const float* x2    = (const float*)d_in[2];
    const float* w_off = (const float*)d_in[3];
    const float* b_off = (const float*)d_in[4];
    const float* w_def = (const float*)d_in[5];
    float* out = (float*)d_out;

    const size_t w2_bytes   = (size_t)(WMAIN_ELEMS + WOFFB_ELEMS) * 2;
    const size_t full_bytes = (XT_ELEMS + WMAIN_ELEMS + WOFFB_ELEMS) * 2;   // ~18 MB

    if (ws_size >= full_bytes) {
        unsigned short* xt = (unsigned short*)d_ws;
        unsigned short* w2 = xt + XT_ELEMS;
        hipLaunchKernelGGL(xprep_kernel, dim3(512), dim3(256), 0, stream, x0, x1, x2, xt);
        hipLaunchKernelGGL(wprep_kernel, dim3((WMAIN_ELEMS + WOFFB_ELEMS) / 256), dim3(256),
                           0, stream, w_def, w_off, w2);
        hipLaunchKernelGGL(deform32_kernel, dim3(1024), dim3(128), 0, stream,
                           xt, b_off, w2, out);
    } else if (ws_size >= w2_bytes) {
        unsigned short* w2 = (unsigned short*)d_ws;
        hipLaunchKernelGGL(wprep_kernel, dim3((WMAIN_ELEMS + WOFFB_ELEMS) / 256), dim3(256),
                           0, stream, w_def, w_off, w2);
        hipLaunchKernelGGL((deform_kernel<true>), dim3(2048), dim3(128), 0, stream,
                           x0, x1, x2, w_off, b_off, w_def, w2, out);
    } else {
        hipLaunchKernelGGL((deform_kernel<false>), dim3(2048), dim3(128), 0, stream,
                           x0, x1, x2, w_off, b_off, w_def, (const unsigned short*)nullptr, out);
    }
}